// Round 12
// baseline (483.555 us; speedup 1.0000x reference)
//
#include <hip/hip_runtime.h>

#define NSRC 50000
#define NTGT 50000
#define NTOT 100000
#define NE   1600000
#define IND  64
#define HD   128
#define CAP  64        // per-node neighbor capacity in part3 LDS (deg ~ Poisson(16); P(>64) ~ 1e-29)
#define NBKT 8         // level-1 dst-range buckets (XCD-aligned)
#define BNODES 12500   // NTOT / NBKT
#define ECAP 204800    // per-bucket edge capacity (mean 200000, +11 sigma); = 25 * 8192
#define PCHUNK 1600    // edges per part8 block
#define PBLKS 1000     // NE / PCHUNK
#define CHUNK2 8192    // edges per part2a/part2b block
#define NCH2 25        // ECAP / CHUNK2
#define SBIN 128       // nodes per bin (level-2)
#define NBIN 782       // ceil(NTOT / 128)
#define NSLICE 8       // feature slices of 16 bf16 (32 B)

typedef short s16x8 __attribute__((ext_vector_type(8)));
typedef float f32x4 __attribute__((ext_vector_type(4)));

__device__ __forceinline__ ushort f2bf(float f) {
  union { float f; uint u; } v; v.f = f;
  const uint r = v.u + 0x7fffu + ((v.u >> 16) & 1u);
  return (ushort)(r >> 16);
}
__device__ __forceinline__ float bfl(uint v) {
  union { uint u; float f; } c; c.u = v << 16; return c.f;
}
__device__ __forceinline__ float bfh(uint v) {
  union { uint u; float f; } c; c.u = v & 0xffff0000u; return c.f;
}
// floor(d / 12500) for d < 100000 via 2^48 magic (verified at all k*12500 boundaries)
__device__ __forceinline__ uint bkt_of(uint d) {
  return (uint)(((unsigned long long)d * 22517998137ull) >> 48);
}
// sliced layout (ushort units): elem(n, c) at ((c>>4)*NTOT + n)*16 + (c&15)

// ---------------- weight conversion f32 -> bf16 (Wl, Wr) ----------------
__global__ __launch_bounds__(256) void cvt2_kernel(const float* __restrict__ a, ushort* __restrict__ oa,
                                                   const float* __restrict__ b, ushort* __restrict__ ob, int n) {
  int i = blockIdx.x * 256 + threadIdx.x;
  const int stride = gridDim.x * 256;
  for (; i < n; i += stride) { oa[i] = f2bf(a[i]); ob[i] = f2bf(b[i]); }
}

// ---------------- MFMA input projection -> SLICED out ----------------
__global__ __launch_bounds__(256) void proj_mfma_kernel(
    const float* __restrict__ x, const float* __restrict__ W,
    const float* __restrict__ b, ushort* __restrict__ out,
    const int count, const int out_base) {
  const int lane = threadIdx.x & 63;
  const int wave = threadIdx.x >> 6;
  const int n0 = blockIdx.x * 128 + wave * 32;
  const int lr = lane & 15;
  const int kc = (lane >> 4) * 8;
  const int rowq = (lane >> 4) * 4;

  s16x8 af[2][2];
#pragma unroll
  for (int r = 0; r < 2; ++r) {
    int ar = n0 + 16 * r + lr;
    if (ar >= count) ar = count - 1;
#pragma unroll
    for (int t = 0; t < 2; ++t) {
      const float* xp = x + (size_t)ar * IND + t * 32 + kc;
      const float4 xa = *(const float4*)(xp);
      const float4 xb = *(const float4*)(xp + 4);
      s16x8 a;
      a[0] = (short)f2bf(xa.x); a[1] = (short)f2bf(xa.y);
      a[2] = (short)f2bf(xa.z); a[3] = (short)f2bf(xa.w);
      a[4] = (short)f2bf(xb.x); a[5] = (short)f2bf(xb.y);
      a[6] = (short)f2bf(xb.z); a[7] = (short)f2bf(xb.w);
      af[r][t] = a;
    }
  }
#pragma unroll
  for (int cf = 0; cf < 8; ++cf) {
    const float* wp = W + (size_t)(cf * 16 + lr) * IND + kc;
    s16x8 w0, w1;
    {
      const float4 wa = *(const float4*)(wp);
      const float4 wb = *(const float4*)(wp + 4);
      const float4 wc = *(const float4*)(wp + 32);
      const float4 wd = *(const float4*)(wp + 36);
      w0[0] = (short)f2bf(wa.x); w0[1] = (short)f2bf(wa.y);
      w0[2] = (short)f2bf(wa.z); w0[3] = (short)f2bf(wa.w);
      w0[4] = (short)f2bf(wb.x); w0[5] = (short)f2bf(wb.y);
      w0[6] = (short)f2bf(wb.z); w0[7] = (short)f2bf(wb.w);
      w1[0] = (short)f2bf(wc.x); w1[1] = (short)f2bf(wc.y);
      w1[2] = (short)f2bf(wc.z); w1[3] = (short)f2bf(wc.w);
      w1[4] = (short)f2bf(wd.x); w1[5] = (short)f2bf(wd.y);
      w1[6] = (short)f2bf(wd.z); w1[7] = (short)f2bf(wd.w);
    }
    f32x4 acc0 = {0.f, 0.f, 0.f, 0.f};
    f32x4 acc1 = {0.f, 0.f, 0.f, 0.f};
    acc0 = __builtin_amdgcn_mfma_f32_16x16x32_bf16(af[0][0], w0, acc0, 0, 0, 0);
    acc1 = __builtin_amdgcn_mfma_f32_16x16x32_bf16(af[1][0], w0, acc1, 0, 0, 0);
    acc0 = __builtin_amdgcn_mfma_f32_16x16x32_bf16(af[0][1], w1, acc0, 0, 0, 0);
    acc1 = __builtin_amdgcn_mfma_f32_16x16x32_bf16(af[1][1], w1, acc1, 0, 0, 0);
    const float bv = b[cf * 16 + lr];
#pragma unroll
    for (int r = 0; r < 2; ++r) {
      const f32x4 acc = r ? acc1 : acc0;
#pragma unroll
      for (int q = 0; q < 4; ++q) {
        const int row = n0 + 16 * r + rowq + q;
        if (row < count)
          out[((size_t)cf * NTOT + (out_base + row)) * 16 + lr] = f2bf(acc[q] + bv);
      }
    }
  }
}

// ---------------- level-1 partition into 8 dst-range buckets ----------------
// Record = src (17b) | dstLocal (14b) << 17.  ebuf lives in d_out (dead early).
__global__ __launch_bounds__(256) void part8_kernel(const int* __restrict__ src, const int* __restrict__ dst,
                                                    uint* __restrict__ cnt8, uint* __restrict__ ebuf) {
  __shared__ uint lcnt[NBKT];
  __shared__ uint lbase[NBKT];
  const int tid = threadIdx.x;
  const int i0 = blockIdx.x * PCHUNK;
  const int i1 = (i0 + PCHUNK < NE) ? i0 + PCHUNK : NE;
  if (tid < NBKT) lcnt[tid] = 0;
  __syncthreads();
  for (int i = i0 + tid; i < i1; i += 256) {
    const uint b = bkt_of((uint)dst[i]);
    atomicAdd(&lcnt[b], 1u);
  }
  __syncthreads();
  if (tid < NBKT) {
    lbase[tid] = atomicAdd(&cnt8[tid], lcnt[tid]);
    lcnt[tid] = 0;   // reuse as local cursor
  }
  __syncthreads();
  for (int i = i0 + tid; i < i1; i += 256) {
    const uint d = (uint)dst[i];
    const uint b = bkt_of(d);
    const uint pos = lbase[b] + atomicAdd(&lcnt[b], 1u);
    if (pos < ECAP) ebuf[(size_t)b * ECAP + pos] = (uint)src[i] | ((d - b * BNODES) << 17);
  }
}

// ---------------- level-2: count per 128-node bin ----------------
__global__ __launch_bounds__(256) void part2a_kernel(const uint* __restrict__ cnt8, const uint* __restrict__ ebuf,
                                                     uint* __restrict__ bincnt) {
  __shared__ uint hist[NBIN];   // 3.1 KB
  const int tid = threadIdx.x;
  const int b = blockIdx.x & (NBKT - 1);
  const int c = blockIdx.x >> 3;
  int n = (int)cnt8[b]; if (n > ECAP) n = ECAP;
  const int i0 = c * CHUNK2;
  const int i1 = (i0 + CHUNK2 < n) ? i0 + CHUNK2 : n;
  for (int j = tid; j < NBIN; j += 256) hist[j] = 0;
  __syncthreads();
  const uint* eb = ebuf + (size_t)b * ECAP;
  for (int i = i0 + tid; i < i1; i += 256) {
    const uint rec = eb[i];
    const uint d = (uint)(b * BNODES) + (rec >> 17);
    atomicAdd(&hist[d >> 7], 1u);
  }
  __syncthreads();
  for (int j = tid; j < NBIN; j += 256)
    if (hist[j]) atomicAdd(&bincnt[j], hist[j]);
}

// ---------------- exclusive scan of bincnt -> binoff (packed, exact); init bincur ----------------
__global__ __launch_bounds__(256) void scan_kernel(const uint* __restrict__ bincnt,
                                                   uint* __restrict__ binoff, uint* __restrict__ bincur) {
  __shared__ uint lds[256];
  const int tid = threadIdx.x;
  uint v[4]; uint s = 0;
#pragma unroll
  for (int j = 0; j < 4; ++j) {
    const int idx = tid * 4 + j;
    v[j] = (idx < NBIN) ? bincnt[idx] : 0;
    s += v[j];
  }
  lds[tid] = s;
  __syncthreads();
  for (int off = 1; off < 256; off <<= 1) {
    const uint t = (tid >= off) ? lds[tid - off] : 0;
    __syncthreads();
    lds[tid] += t;
    __syncthreads();
  }
  uint run = lds[tid] - s;  // exclusive
#pragma unroll
  for (int j = 0; j < 4; ++j) {
    const int idx = tid * 4 + j;
    if (idx < NBIN) { binoff[idx] = run; bincur[idx] = run; }
    else if (idx == NBIN) binoff[idx] = run;
    run += v[j];
  }
}

// ---------------- level-2 scatter: ebuf -> ebuf2 grouped by bin (ranked, packed) ----------------
// Record out = src (17b) | binLocal (7b) << 17.
__global__ __launch_bounds__(256) void part2b_kernel(const uint* __restrict__ cnt8, const uint* __restrict__ ebuf,
                                                     uint* __restrict__ bincur, uint* __restrict__ ebuf2) {
  __shared__ uint hist[NBIN];   // 3.1 KB
  __shared__ uint base[NBIN];   // 3.1 KB
  const int tid = threadIdx.x;
  const int b = blockIdx.x & (NBKT - 1);
  const int c = blockIdx.x >> 3;
  int n = (int)cnt8[b]; if (n > ECAP) n = ECAP;
  const int i0 = c * CHUNK2;
  const int i1 = (i0 + CHUNK2 < n) ? i0 + CHUNK2 : n;
  for (int j = tid; j < NBIN; j += 256) hist[j] = 0;
  __syncthreads();
  const uint* eb = ebuf + (size_t)b * ECAP;
  for (int i = i0 + tid; i < i1; i += 256) {
    const uint rec = eb[i];
    const uint d = (uint)(b * BNODES) + (rec >> 17);
    atomicAdd(&hist[d >> 7], 1u);
  }
  __syncthreads();
  for (int j = tid; j < NBIN; j += 256) {
    if (hist[j]) base[j] = atomicAdd(&bincur[j], hist[j]);
    hist[j] = 0;   // reuse as local cursor
  }
  __syncthreads();
  for (int i = i0 + tid; i < i1; i += 256) {
    const uint rec = eb[i];
    const uint d = (uint)(b * BNODES) + (rec >> 17);
    const uint bin = d >> 7;
    const uint pos = base[bin] + atomicAdd(&hist[bin], 1u);
    ebuf2[pos] = (rec & 0x1FFFFu) | ((d & 127u) << 17);
  }
}

// ---------------- part3: node-sort each bin's records -> CSR (csr + rowstart) ----------------
// One block per 128-node bin: LDS scatter to per-node lists, scan counts, compact out.
__global__ __launch_bounds__(256) void part3_kernel(const uint* __restrict__ binoff, const uint* __restrict__ ebuf2,
                                                    uint* __restrict__ csr, int* __restrict__ rowstart) {
  __shared__ uint slotL[SBIN][CAP];   // 32 KB
  __shared__ uint cntL[SBIN];
  __shared__ uint scanL[SBIN];
  const int tid = threadIdx.x;
  const int b = blockIdx.x;
  const int e0 = (int)binoff[b];
  const int e1 = (int)binoff[b + 1];
  for (int j = tid; j < SBIN; j += 256) cntL[j] = 0;
  __syncthreads();
  for (int i = e0 + tid; i < e1; i += 256) {
    const uint rec = ebuf2[i];
    const uint dl = rec >> 17;
    const uint pos = atomicAdd(&cntL[dl], 1u);
    if (pos < CAP) slotL[dl][pos] = rec & 0x1FFFFu;
  }
  __syncthreads();
  // inclusive scan of clamped counts over 128 entries (Hillis-Steele in LDS)
  if (tid < SBIN) {
    uint cv = cntL[tid];
    scanL[tid] = cv < CAP ? cv : CAP;
  }
  __syncthreads();
  for (int off = 1; off < SBIN; off <<= 1) {
    uint t = 0;
    if (tid < SBIN && tid >= off) t = scanL[tid - off];
    __syncthreads();
    if (tid < SBIN) scanL[tid] += t;
    __syncthreads();
  }
  // compact write + rowstart
  if (tid < SBIN) {
    const int node = b * SBIN + tid;
    const uint m = (cntL[tid] < CAP) ? cntL[tid] : CAP;
    const uint myoff = (uint)e0 + scanL[tid] - m;   // exclusive
    if (node < NTOT) {
      rowstart[node] = (int)myoff;
      for (uint j = 0; j < m; ++j) csr[myoff + j] = slotL[tid][j];
    }
  }
  if (b == NBIN - 1 && tid == 0) rowstart[NTOT] = e0 + (int)scanL[SBIN - 1];
}

// ---------------- sliced mean aggregation ----------------
// Block (bin, slice): slice s = bid&7 -> XCD s (round-robin); per-XCD h footprint =
// NTOT*32B = 3.2 MB, L2-resident. 256 threads = 128 lane-pairs, pair p owns node
// bin*128+p: sequential CSR walk, 4 gathers of 16B in flight, no LDS, no shuffles.
__global__ __launch_bounds__(256) void agg_slice_kernel(const ushort* __restrict__ hsl,
                                                        ushort* __restrict__ asl,
                                                        const int* __restrict__ rowstart,
                                                        const uint* __restrict__ csr) {
  const int s = blockIdx.x & (NSLICE - 1);
  const int bin = blockIdx.x >> 3;
  const int p = threadIdx.x >> 1;
  const int half = threadIdx.x & 1;
  const int n = bin * SBIN + p;
  if (n >= NTOT) return;
  const int r0 = rowstart[n];
  const int r1 = rowstart[n + 1];
  const ushort* hb = hsl + (size_t)s * NTOT * 16 + half * 8;
  float a0 = 0.f, a1 = 0.f, a2 = 0.f, a3 = 0.f, a4 = 0.f, a5 = 0.f, a6 = 0.f, a7 = 0.f;
#define ACC8(v) { a0 += bfl((v).x); a1 += bfh((v).x); a2 += bfl((v).y); a3 += bfh((v).y); \
                  a4 += bfl((v).z); a5 += bfh((v).z); a6 += bfl((v).w); a7 += bfh((v).w); }
  int i = r0;
  for (; i + 4 <= r1; i += 4) {
    const uint s0 = csr[i], s1 = csr[i + 1], s2 = csr[i + 2], s3 = csr[i + 3];
    const uint4 v0 = *(const uint4*)(hb + (size_t)s0 * 16);
    const uint4 v1 = *(const uint4*)(hb + (size_t)s1 * 16);
    const uint4 v2 = *(const uint4*)(hb + (size_t)s2 * 16);
    const uint4 v3 = *(const uint4*)(hb + (size_t)s3 * 16);
    ACC8(v0); ACC8(v1); ACC8(v2); ACC8(v3);
  }
  for (; i < r1; ++i) {
    const uint4 v = *(const uint4*)(hb + (size_t)csr[i] * 16);
    ACC8(v);
  }
#undef ACC8
  const int deg = r1 - r0;
  const float sc = 1.0f / (float)(deg > 1 ? deg : 1);
  uint4 o;
  o.x = (uint)f2bf(a0 * sc) | ((uint)f2bf(a1 * sc) << 16);
  o.y = (uint)f2bf(a2 * sc) | ((uint)f2bf(a3 * sc) << 16);
  o.z = (uint)f2bf(a4 * sc) | ((uint)f2bf(a5 * sc) << 16);
  o.w = (uint)f2bf(a6 * sc) | ((uint)f2bf(a7 * sc) << 16);
  *(uint4*)(asl + ((size_t)s * NTOT + n) * 16 + half * 8) = o;
}

// ---------------- MFMA dual GEMM (SLICED A/Hm): out = A@Wl^T + bl + Hm@Wr^T ----------------
// In-place safe (out may alias A): each wave loads its own 32 rows before any store.
__global__ __launch_bounds__(256) void mfma_gemm_kernel(
    const ushort* A, const ushort* Hm,
    const ushort* __restrict__ Wl, const float* __restrict__ bl,
    const ushort* __restrict__ Wr, void* outv,
    const int relu, const int f32out) {
  const int lane = threadIdx.x & 63;
  const int wave = threadIdx.x >> 6;
  const int n0 = blockIdx.x * 128 + wave * 32;
  const int lr = lane & 15;
  const int kc = (lane >> 4) * 8;
  const int rowq = (lane >> 4) * 4;

  s16x8 af[2][4], hf[2][4];
#pragma unroll
  for (int r = 0; r < 2; ++r) {
    int ar = n0 + 16 * r + lr;
    if (ar >= NTOT) ar = NTOT - 1;     // clamped lanes never store
#pragma unroll
    for (int t = 0; t < 4; ++t) {
      const size_t sl = (size_t)(2 * t + (kc >> 4));
      const int io = kc & 8;
      af[r][t] = *(const s16x8*)(A + (sl * NTOT + ar) * 16 + io);
      hf[r][t] = *(const s16x8*)(Hm + (sl * NTOT + ar) * 16 + io);
    }
  }

#pragma unroll
  for (int cf = 0; cf < 8; ++cf) {
    const ushort* wlp = Wl + (size_t)(cf * 16 + lr) * HD + kc;
    const ushort* wrp = Wr + (size_t)(cf * 16 + lr) * HD + kc;
    s16x8 wl[4], wr[4];
#pragma unroll
    for (int t = 0; t < 4; ++t) {
      wl[t] = *(const s16x8*)(wlp + t * 32);
      wr[t] = *(const s16x8*)(wrp + t * 32);
    }
    f32x4 acc0 = {0.f, 0.f, 0.f, 0.f};
    f32x4 acc1 = {0.f, 0.f, 0.f, 0.f};
#pragma unroll
    for (int t = 0; t < 4; ++t) {
      acc0 = __builtin_amdgcn_mfma_f32_16x16x32_bf16(af[0][t], wl[t], acc0, 0, 0, 0);
      acc1 = __builtin_amdgcn_mfma_f32_16x16x32_bf16(af[1][t], wl[t], acc1, 0, 0, 0);
      acc0 = __builtin_amdgcn_mfma_f32_16x16x32_bf16(hf[0][t], wr[t], acc0, 0, 0, 0);
      acc1 = __builtin_amdgcn_mfma_f32_16x16x32_bf16(hf[1][t], wr[t], acc1, 0, 0, 0);
    }
    const float bv = bl[cf * 16 + lr];
#pragma unroll
    for (int r = 0; r < 2; ++r) {
      const f32x4 acc = r ? acc1 : acc0;
#pragma unroll
      for (int q = 0; q < 4; ++q) {
        const int row = n0 + 16 * r + rowq + q;
        if (row < NTOT) {
          float v = acc[q] + bv;
          if (relu && v < 0.f) v = 0.f;
          if (f32out) ((float*)outv)[(size_t)row * HD + cf * 16 + lr] = v;       // row-major f32
          else        ((ushort*)outv)[((size_t)cf * NTOT + row) * 16 + lr] = f2bf(v);  // sliced bf16
        }
      }
    }
  }
}

extern "C" void kernel_launch(void* const* d_in, const int* in_sizes, int n_in,
                              void* d_out, int out_size, void* d_ws, size_t ws_size,
                              hipStream_t stream) {
  const float* src_x = (const float*)d_in[0];
  const float* tgt_x = (const float*)d_in[1];
  const int*   eidx  = (const int*)d_in[2];
  const float* Wsrc  = (const float*)d_in[3];
  const float* bsrc  = (const float*)d_in[4];
  const float* Wtgt  = (const float*)d_in[5];
  const float* btgt  = (const float*)d_in[6];
  const float* Wl    = (const float*)d_in[7];
  const float* bl    = (const float*)d_in[8];
  const float* Wr    = (const float*)d_in[9];
  float* out = (float*)d_out;
  (void)in_sizes; (void)n_in; (void)out_size; (void)ws_size;

  // ws ~52 MB (under round-2-proven ~59.4 MB)
  char* ws = (char*)d_ws;
  size_t off = 0;
  auto alloc = [&](size_t bytes) -> void* {
    void* p = (void*)(ws + off);
    off = (off + bytes + 511) & ~(size_t)511;
    return p;
  };
  ushort* hbuf   = (ushort*)alloc((size_t)NTOT * HD * sizeof(ushort));  // 25.6 MB (sliced)
  ushort* abuf   = (ushort*)alloc((size_t)NTOT * HD * sizeof(ushort));  // 25.6 MB (sliced)
  ushort* wlb    = (ushort*)alloc((size_t)3 * HD * HD * sizeof(ushort));
  ushort* wrb    = (ushort*)alloc((size_t)3 * HD * HD * sizeof(ushort));
  uint*   cnt8   = (uint*)alloc(NBKT * sizeof(uint));
  uint*   bincnt = (uint*)alloc(NBIN * sizeof(uint));
  uint*   binoff = (uint*)alloc((NBIN + 1) * sizeof(uint));
  uint*   bincur = (uint*)alloc(NBIN * sizeof(uint));

  // Transient graph structures live in d_out (51.2 MB); all are dead (fully read)
  // before the final gemm overwrites d_out (stream-ordered).
  uint* dout_u   = (uint*)d_out;
  uint* ebuf     = dout_u;                 // [0, 1,638,400)        6.55 MB
  uint* ebuf2    = dout_u + 1700000;       // [1.7M, 3.3M)          6.4 MB
  uint* csr      = dout_u + 3400000;       // [3.4M, 5.0M)          6.4 MB
  int*  rowstart = (int*)(dout_u + 5100000); // [5.1M, 5.2M)        400 KB

  const int* src_idx = eidx;
  const int* dst_idx = eidx + NE;

  hipMemsetAsync(cnt8, 0, NBKT * sizeof(uint), stream);
  hipMemsetAsync(bincnt, 0, NBIN * sizeof(uint), stream);

  cvt2_kernel<<<192, 256, 0, stream>>>(Wl, wlb, Wr, wrb, 3 * HD * HD);

  proj_mfma_kernel<<<(NSRC + 127) / 128, 256, 0, stream>>>(src_x, Wsrc, bsrc, hbuf, NSRC, 0);
  proj_mfma_kernel<<<(NTGT + 127) / 128, 256, 0, stream>>>(tgt_x, Wtgt, btgt, hbuf, NTGT, NSRC);

  part8_kernel<<<PBLKS, 256, 0, stream>>>(src_idx, dst_idx, cnt8, ebuf);
  part2a_kernel<<<NBKT * NCH2, 256, 0, stream>>>(cnt8, ebuf, bincnt);
  scan_kernel<<<1, 256, 0, stream>>>(bincnt, binoff, bincur);
  part2b_kernel<<<NBKT * NCH2, 256, 0, stream>>>(cnt8, ebuf, bincur, ebuf2);
  part3_kernel<<<NBIN, 256, 0, stream>>>(binoff, ebuf2, csr, rowstart);

  const int agrid = NBIN * NSLICE;
  const int ggrid = (NTOT + 127) / 128;
  // layer 0: hbuf -> agg(abuf) -> gemm in place over abuf
  agg_slice_kernel<<<agrid, 256, 0, stream>>>(hbuf, abuf, rowstart, csr);
  mfma_gemm_kernel<<<ggrid, 256, 0, stream>>>(abuf, hbuf, wlb, bl, wrb, abuf, 1, 0);
  // layer 1: abuf -> agg(hbuf) -> gemm in place over hbuf
  agg_slice_kernel<<<agrid, 256, 0, stream>>>(abuf, hbuf, rowstart, csr);
  mfma_gemm_kernel<<<ggrid, 256, 0, stream>>>(hbuf, abuf, wlb + HD * HD, bl + HD, wrb + HD * HD, hbuf, 1, 0);
  // layer 2: hbuf -> agg(abuf) -> gemm -> d_out (f32, no relu); all d_out transients dead here
  agg_slice_kernel<<<agrid, 256, 0, stream>>>(hbuf, abuf, rowstart, csr);
  mfma_gemm_kernel<<<ggrid, 256, 0, stream>>>(abuf, hbuf, wlb + 2 * HD * HD, bl + 2 * HD, wrb + 2 * HD * HD, out, 0, 1);
}

// Round 13
// 411.707 us; speedup vs baseline: 1.1745x; 1.1745x over previous
//
#include <hip/hip_runtime.h>

#define NSRC 50000
#define NTGT 50000
#define NTOT 100000
#define NE   1600000
#define IND  64
#define HD   128
#define CAP  64        // per-node neighbor capacity in part3 LDS (deg ~ Poisson(16); P(>64) ~ 1e-29)
#define NBKT 8         // level-1 dst-range buckets (XCD-aligned)
#define BNODES 12500   // NTOT / NBKT
#define ECAP 204800    // per-bucket edge capacity (mean 200000, +11 sigma); = 25 * 8192
#define PCHUNK 1600    // edges per part8 block
#define PBLKS 1000     // NE / PCHUNK
#define CHUNK2 8192    // edges per part2a/part2b block
#define NCH2 25        // ECAP / CHUNK2
#define SBIN 128       // nodes per level-2 bin
#define NBIN 782       // ceil(NTOT / 128)

typedef short s16x8 __attribute__((ext_vector_type(8)));
typedef float f32x4 __attribute__((ext_vector_type(4)));

__device__ __forceinline__ ushort f2bf(float f) {
  union { float f; uint u; } v; v.f = f;
  const uint r = v.u + 0x7fffu + ((v.u >> 16) & 1u);
  return (ushort)(r >> 16);
}
__device__ __forceinline__ float bfl(uint v) {
  union { uint u; float f; } c; c.u = v << 16; return c.f;
}
__device__ __forceinline__ float bfh(uint v) {
  union { uint u; float f; } c; c.u = v & 0xffff0000u; return c.f;
}
// floor(d / 12500) for d < 100000 via 2^48 magic (verified at all k*12500 boundaries)
__device__ __forceinline__ uint bkt_of(uint d) {
  return (uint)(((unsigned long long)d * 22517998137ull) >> 48);
}

// ---------------- weight conversion f32 -> bf16 (Wl, Wr) ----------------
__global__ __launch_bounds__(256) void cvt2_kernel(const float* __restrict__ a, ushort* __restrict__ oa,
                                                   const float* __restrict__ b, ushort* __restrict__ ob, int n) {
  int i = blockIdx.x * 256 + threadIdx.x;
  const int stride = gridDim.x * 256;
  for (; i < n; i += stride) { oa[i] = f2bf(a[i]); ob[i] = f2bf(b[i]); }
}

// ---------------- MFMA input projection: out[n][f] = bf16(b[f] + x[n][:] @ W[f][:]) ----------------
// W stays f32 (tiny, L2-hot), converted in-register. Block = 128 rows, 4 waves x 32 rows.
__global__ __launch_bounds__(256) void proj_mfma_kernel(
    const float* __restrict__ x, const float* __restrict__ W,
    const float* __restrict__ b, ushort* __restrict__ out,
    const int count, const int out_base) {
  const int lane = threadIdx.x & 63;
  const int wave = threadIdx.x >> 6;
  const int n0 = blockIdx.x * 128 + wave * 32;
  const int lr = lane & 15;
  const int kc = (lane >> 4) * 8;
  const int rowq = (lane >> 4) * 4;

  s16x8 af[2][2];
#pragma unroll
  for (int r = 0; r < 2; ++r) {
    int ar = n0 + 16 * r + lr;
    if (ar >= count) ar = count - 1;
#pragma unroll
    for (int t = 0; t < 2; ++t) {
      const float* xp = x + (size_t)ar * IND + t * 32 + kc;
      const float4 xa = *(const float4*)(xp);
      const float4 xb = *(const float4*)(xp + 4);
      s16x8 a;
      a[0] = (short)f2bf(xa.x); a[1] = (short)f2bf(xa.y);
      a[2] = (short)f2bf(xa.z); a[3] = (short)f2bf(xa.w);
      a[4] = (short)f2bf(xb.x); a[5] = (short)f2bf(xb.y);
      a[6] = (short)f2bf(xb.z); a[7] = (short)f2bf(xb.w);
      af[r][t] = a;
    }
  }
#pragma unroll
  for (int cf = 0; cf < 8; ++cf) {
    const float* wp = W + (size_t)(cf * 16 + lr) * IND + kc;
    s16x8 w0, w1;
    {
      const float4 wa = *(const float4*)(wp);
      const float4 wb = *(const float4*)(wp + 4);
      const float4 wc = *(const float4*)(wp + 32);
      const float4 wd = *(const float4*)(wp + 36);
      w0[0] = (short)f2bf(wa.x); w0[1] = (short)f2bf(wa.y);
      w0[2] = (short)f2bf(wa.z); w0[3] = (short)f2bf(wa.w);
      w0[4] = (short)f2bf(wb.x); w0[5] = (short)f2bf(wb.y);
      w0[6] = (short)f2bf(wb.z); w0[7] = (short)f2bf(wb.w);
      w1[0] = (short)f2bf(wc.x); w1[1] = (short)f2bf(wc.y);
      w1[2] = (short)f2bf(wc.z); w1[3] = (short)f2bf(wc.w);
      w1[4] = (short)f2bf(wd.x); w1[5] = (short)f2bf(wd.y);
      w1[6] = (short)f2bf(wd.z); w1[7] = (short)f2bf(wd.w);
    }
    f32x4 acc0 = {0.f, 0.f, 0.f, 0.f};
    f32x4 acc1 = {0.f, 0.f, 0.f, 0.f};
    acc0 = __builtin_amdgcn_mfma_f32_16x16x32_bf16(af[0][0], w0, acc0, 0, 0, 0);
    acc1 = __builtin_amdgcn_mfma_f32_16x16x32_bf16(af[1][0], w0, acc1, 0, 0, 0);
    acc0 = __builtin_amdgcn_mfma_f32_16x16x32_bf16(af[0][1], w1, acc0, 0, 0, 0);
    acc1 = __builtin_amdgcn_mfma_f32_16x16x32_bf16(af[1][1], w1, acc1, 0, 0, 0);
    const int col = cf * 16 + lr;
    const float bv = b[col];
#pragma unroll
    for (int r = 0; r < 2; ++r) {
      const f32x4 acc = r ? acc1 : acc0;
#pragma unroll
      for (int q = 0; q < 4; ++q) {
        const int row = n0 + 16 * r + rowq + q;
        if (row < count) out[(size_t)(out_base + row) * HD + col] = f2bf(acc[q] + bv);
      }
    }
  }
}

// ---------------- level-1 partition into 8 dst-range buckets ----------------
// Record = src (17b) | dstLocal (14b) << 17.  ebuf lives in d_out (dead early).
__global__ __launch_bounds__(256) void part8_kernel(const int* __restrict__ src, const int* __restrict__ dst,
                                                    uint* __restrict__ cnt8, uint* __restrict__ ebuf) {
  __shared__ uint lcnt[NBKT];
  __shared__ uint lbase[NBKT];
  const int tid = threadIdx.x;
  const int i0 = blockIdx.x * PCHUNK;
  const int i1 = (i0 + PCHUNK < NE) ? i0 + PCHUNK : NE;
  if (tid < NBKT) lcnt[tid] = 0;
  __syncthreads();
  for (int i = i0 + tid; i < i1; i += 256) {
    const uint b = bkt_of((uint)dst[i]);
    atomicAdd(&lcnt[b], 1u);
  }
  __syncthreads();
  if (tid < NBKT) {
    lbase[tid] = atomicAdd(&cnt8[tid], lcnt[tid]);
    lcnt[tid] = 0;   // reuse as local cursor
  }
  __syncthreads();
  for (int i = i0 + tid; i < i1; i += 256) {
    const uint d = (uint)dst[i];
    const uint b = bkt_of(d);
    const uint pos = lbase[b] + atomicAdd(&lcnt[b], 1u);
    if (pos < ECAP) ebuf[(size_t)b * ECAP + pos] = (uint)src[i] | ((d - b * BNODES) << 17);
  }
}

// ---------------- level-2: count per 128-node bin ----------------
__global__ __launch_bounds__(256) void part2a_kernel(const uint* __restrict__ cnt8, const uint* __restrict__ ebuf,
                                                     uint* __restrict__ bincnt) {
  __shared__ uint hist[NBIN];   // 3.1 KB
  const int tid = threadIdx.x;
  const int b = blockIdx.x & (NBKT - 1);
  const int c = blockIdx.x >> 3;
  int n = (int)cnt8[b]; if (n > ECAP) n = ECAP;
  const int i0 = c * CHUNK2;
  const int i1 = (i0 + CHUNK2 < n) ? i0 + CHUNK2 : n;
  for (int j = tid; j < NBIN; j += 256) hist[j] = 0;
  __syncthreads();
  const uint* eb = ebuf + (size_t)b * ECAP;
  for (int i = i0 + tid; i < i1; i += 256) {
    const uint rec = eb[i];
    const uint d = (uint)(b * BNODES) + (rec >> 17);
    atomicAdd(&hist[d >> 7], 1u);
  }
  __syncthreads();
  for (int j = tid; j < NBIN; j += 256)
    if (hist[j]) atomicAdd(&bincnt[j], hist[j]);
}

// ---------------- exclusive scan of bincnt -> binoff (packed, exact); init bincur ----------------
__global__ __launch_bounds__(256) void scan_kernel(const uint* __restrict__ bincnt,
                                                   uint* __restrict__ binoff, uint* __restrict__ bincur) {
  __shared__ uint lds[256];
  const int tid = threadIdx.x;
  uint v[4]; uint s = 0;
#pragma unroll
  for (int j = 0; j < 4; ++j) {
    const int idx = tid * 4 + j;
    v[j] = (idx < NBIN) ? bincnt[idx] : 0;
    s += v[j];
  }
  lds[tid] = s;
  __syncthreads();
  for (int off = 1; off < 256; off <<= 1) {
    const uint t = (tid >= off) ? lds[tid - off] : 0;
    __syncthreads();
    lds[tid] += t;
    __syncthreads();
  }
  uint run = lds[tid] - s;  // exclusive
#pragma unroll
  for (int j = 0; j < 4; ++j) {
    const int idx = tid * 4 + j;
    if (idx < NBIN) { binoff[idx] = run; bincur[idx] = run; }
    else if (idx == NBIN) binoff[idx] = run;
    run += v[j];
  }
}

// ---------------- level-2 scatter: ebuf -> ebuf2 grouped by bin (ranked, packed) ----------------
// Record out = src (17b) | binLocal (7b) << 17.
__global__ __launch_bounds__(256) void part2b_kernel(const uint* __restrict__ cnt8, const uint* __restrict__ ebuf,
                                                     uint* __restrict__ bincur, uint* __restrict__ ebuf2) {
  __shared__ uint hist[NBIN];   // 3.1 KB
  __shared__ uint base[NBIN];   // 3.1 KB
  const int tid = threadIdx.x;
  const int b = blockIdx.x & (NBKT - 1);
  const int c = blockIdx.x >> 3;
  int n = (int)cnt8[b]; if (n > ECAP) n = ECAP;
  const int i0 = c * CHUNK2;
  const int i1 = (i0 + CHUNK2 < n) ? i0 + CHUNK2 : n;
  for (int j = tid; j < NBIN; j += 256) hist[j] = 0;
  __syncthreads();
  const uint* eb = ebuf + (size_t)b * ECAP;
  for (int i = i0 + tid; i < i1; i += 256) {
    const uint rec = eb[i];
    const uint d = (uint)(b * BNODES) + (rec >> 17);
    atomicAdd(&hist[d >> 7], 1u);
  }
  __syncthreads();
  for (int j = tid; j < NBIN; j += 256) {
    if (hist[j]) base[j] = atomicAdd(&bincur[j], hist[j]);
    hist[j] = 0;   // reuse as local cursor
  }
  __syncthreads();
  for (int i = i0 + tid; i < i1; i += 256) {
    const uint rec = eb[i];
    const uint d = (uint)(b * BNODES) + (rec >> 17);
    const uint bin = d >> 7;
    const uint pos = base[bin] + atomicAdd(&hist[bin], 1u);
    ebuf2[pos] = (rec & 0x1FFFFu) | ((d & 127u) << 17);
  }
}

// ---------------- part3: node-sort each bin's records -> CSR (csr + rowstart), built ONCE ----------------
__global__ __launch_bounds__(256) void part3_kernel(const uint* __restrict__ binoff, const uint* __restrict__ ebuf2,
                                                    uint* __restrict__ csr, int* __restrict__ rowstart) {
  __shared__ uint slotL[SBIN][CAP];   // 32 KB
  __shared__ uint cntL[SBIN];
  __shared__ uint scanL[SBIN];
  const int tid = threadIdx.x;
  const int b = blockIdx.x;
  const int e0 = (int)binoff[b];
  const int e1 = (int)binoff[b + 1];
  for (int j = tid; j < SBIN; j += 256) cntL[j] = 0;
  __syncthreads();
  for (int i = e0 + tid; i < e1; i += 256) {
    const uint rec = ebuf2[i];
    const uint dl = rec >> 17;
    const uint pos = atomicAdd(&cntL[dl], 1u);
    if (pos < CAP) slotL[dl][pos] = rec & 0x1FFFFu;
  }
  __syncthreads();
  if (tid < SBIN) {
    uint cv = cntL[tid];
    scanL[tid] = cv < CAP ? cv : CAP;
  }
  __syncthreads();
  for (int off = 1; off < SBIN; off <<= 1) {
    uint t = 0;
    if (tid < SBIN && tid >= off) t = scanL[tid - off];
    __syncthreads();
    if (tid < SBIN) scanL[tid] += t;
    __syncthreads();
  }
  if (tid < SBIN) {
    const int node = b * SBIN + tid;
    const uint m = (cntL[tid] < CAP) ? cntL[tid] : CAP;
    const uint myoff = (uint)e0 + scanL[tid] - m;   // exclusive
    if (node < NTOT) {
      rowstart[node] = (int)myoff;
      for (uint j = 0; j < m; ++j) csr[myoff + j] = slotL[tid][j];
    }
  }
  if (b == NBIN - 1 && tid == 0) rowstart[NTOT] = e0 + (int)scanL[SBIN - 1];
}

// ---------------- CSR-direct mean aggregation: 16-lane group per node, zero LDS ----------------
// Grid 6250 x 256 (16 nodes/block, 24.4 blocks/CU -> smooth tail, high occupancy).
// Per group: uniform csr reads (same-address broadcast), 4 full 256B rows in flight.
__global__ __launch_bounds__(256) void agg4_kernel(const ushort* __restrict__ h, ushort* __restrict__ agg,
                                                   const int* __restrict__ rowstart, const uint* __restrict__ csr) {
  const int g = threadIdx.x >> 4;        // 0..15
  const int l16 = threadIdx.x & 15;
  const int n = blockIdx.x * 16 + g;     // 6250*16 = 100000 exact
  const int r0 = rowstart[n];
  const int r1 = rowstart[n + 1];
  const uint4* hp = (const uint4*)h;     // row = 16 uint4 (128 bf16)
  float a0 = 0.f, a1 = 0.f, a2 = 0.f, a3 = 0.f, a4 = 0.f, a5 = 0.f, a6 = 0.f, a7 = 0.f;
#define ACC8(v) { a0 += bfl((v).x); a1 += bfh((v).x); a2 += bfl((v).y); a3 += bfh((v).y); \
                  a4 += bfl((v).z); a5 += bfh((v).z); a6 += bfl((v).w); a7 += bfh((v).w); }
  int i = r0;
  for (; i + 4 <= r1; i += 4) {
    const uint s0 = csr[i], s1 = csr[i + 1], s2 = csr[i + 2], s3 = csr[i + 3];
    const uint4 v0 = hp[(size_t)s0 * 16 + l16];
    const uint4 v1 = hp[(size_t)s1 * 16 + l16];
    const uint4 v2 = hp[(size_t)s2 * 16 + l16];
    const uint4 v3 = hp[(size_t)s3 * 16 + l16];
    ACC8(v0); ACC8(v1); ACC8(v2); ACC8(v3);
  }
  for (; i < r1; ++i) {
    const uint4 v = hp[(size_t)csr[i] * 16 + l16];
    ACC8(v);
  }
#undef ACC8
  const int deg = r1 - r0;
  const float sc = 1.0f / (float)(deg > 1 ? deg : 1);
  uint4 o;
  o.x = (uint)f2bf(a0 * sc) | ((uint)f2bf(a1 * sc) << 16);
  o.y = (uint)f2bf(a2 * sc) | ((uint)f2bf(a3 * sc) << 16);
  o.z = (uint)f2bf(a4 * sc) | ((uint)f2bf(a5 * sc) << 16);
  o.w = (uint)f2bf(a6 * sc) | ((uint)f2bf(a7 * sc) << 16);
  ((uint4*)agg)[(size_t)n * 16 + l16] = o;
}

// ---------------- MFMA dual GEMM: out = A@Wl^T + bl + Hm@Wr^T (opt relu, opt f32 out) ----------------
// Block = 128 rows, 4 waves; each wave owns 32 rows x all 128 cols. No LDS.
// In-place safe (out may alias A): each wave loads its own 32 rows into registers
// before any store; no __restrict__ on aliasing pointers.
__global__ __launch_bounds__(256) void mfma_gemm_kernel(
    const ushort* A, const ushort* Hm,
    const ushort* __restrict__ Wl, const float* __restrict__ bl,
    const ushort* __restrict__ Wr, void* outv,
    const int relu, const int f32out) {
  const int lane = threadIdx.x & 63;
  const int wave = threadIdx.x >> 6;
  const int n0 = blockIdx.x * 128 + wave * 32;
  const int lr = lane & 15;
  const int kc = (lane >> 4) * 8;
  const int rowq = (lane >> 4) * 4;

  s16x8 af[2][4], hf[2][4];
#pragma unroll
  for (int r = 0; r < 2; ++r) {
    int ar = n0 + 16 * r + lr;
    if (ar >= NTOT) ar = NTOT - 1;     // clamped lanes never store
    const ushort* ap = A + (size_t)ar * HD + kc;
    const ushort* hp = Hm + (size_t)ar * HD + kc;
#pragma unroll
    for (int t = 0; t < 4; ++t) {
      af[r][t] = *(const s16x8*)(ap + t * 32);
      hf[r][t] = *(const s16x8*)(hp + t * 32);
    }
  }

#pragma unroll
  for (int cf = 0; cf < 8; ++cf) {
    const ushort* wlp = Wl + (size_t)(cf * 16 + lr) * HD + kc;
    const ushort* wrp = Wr + (size_t)(cf * 16 + lr) * HD + kc;
    s16x8 wl[4], wr[4];
#pragma unroll
    for (int t = 0; t < 4; ++t) {
      wl[t] = *(const s16x8*)(wlp + t * 32);
      wr[t] = *(const s16x8*)(wrp + t * 32);
    }
    f32x4 acc0 = {0.f, 0.f, 0.f, 0.f};
    f32x4 acc1 = {0.f, 0.f, 0.f, 0.f};
#pragma unroll
    for (int t = 0; t < 4; ++t) {
      acc0 = __builtin_amdgcn_mfma_f32_16x16x32_bf16(af[0][t], wl[t], acc0, 0, 0, 0);
      acc1 = __builtin_amdgcn_mfma_f32_16x16x32_bf16(af[1][t], wl[t], acc1, 0, 0, 0);
      acc0 = __builtin_amdgcn_mfma_f32_16x16x32_bf16(hf[0][t], wr[t], acc0, 0, 0, 0);
      acc1 = __builtin_amdgcn_mfma_f32_16x16x32_bf16(hf[1][t], wr[t], acc1, 0, 0, 0);
    }
    const float bv = bl[cf * 16 + lr];
    const int col = cf * 16 + lr;
#pragma unroll
    for (int r = 0; r < 2; ++r) {
      const f32x4 acc = r ? acc1 : acc0;
#pragma unroll
      for (int q = 0; q < 4; ++q) {
        const int row = n0 + 16 * r + rowq + q;
        if (row < NTOT) {
          float v = acc[q] + bv;
          if (relu && v < 0.f) v = 0.f;
          if (f32out) ((float*)outv)[(size_t)row * HD + col] = v;
          else        ((ushort*)outv)[(size_t)row * HD + col] = f2bf(v);
        }
      }
    }
  }
}

extern "C" void kernel_launch(void* const* d_in, const int* in_sizes, int n_in,
                              void* d_out, int out_size, void* d_ws, size_t ws_size,
                              hipStream_t stream) {
  const float* src_x = (const float*)d_in[0];
  const float* tgt_x = (const float*)d_in[1];
  const int*   eidx  = (const int*)d_in[2];
  const float* Wsrc  = (const float*)d_in[3];
  const float* bsrc  = (const float*)d_in[4];
  const float* Wtgt  = (const float*)d_in[5];
  const float* btgt  = (const float*)d_in[6];
  const float* Wl    = (const float*)d_in[7];
  const float* bl    = (const float*)d_in[8];
  const float* Wr    = (const float*)d_in[9];
  float* out = (float*)d_out;
  (void)in_sizes; (void)n_in; (void)out_size; (void)ws_size;

  // ws ~52 MB (under round-2-proven ~59.4 MB)
  char* ws = (char*)d_ws;
  size_t off = 0;
  auto alloc = [&](size_t bytes) -> void* {
    void* p = (void*)(ws + off);
    off = (off + bytes + 511) & ~(size_t)511;
    return p;
  };
  ushort* hbuf   = (ushort*)alloc((size_t)NTOT * HD * sizeof(ushort));  // 25.6 MB (row-major)
  ushort* abuf   = (ushort*)alloc((size_t)NTOT * HD * sizeof(ushort));  // 25.6 MB (row-major)
  ushort* wlb    = (ushort*)alloc((size_t)3 * HD * HD * sizeof(ushort));
  ushort* wrb    = (ushort*)alloc((size_t)3 * HD * HD * sizeof(ushort));
  uint*   cnt8   = (uint*)alloc(NBKT * sizeof(uint));
  uint*   bincnt = (uint*)alloc(NBIN * sizeof(uint));
  uint*   binoff = (uint*)alloc((NBIN + 1) * sizeof(uint));
  uint*   bincur = (uint*)alloc(NBIN * sizeof(uint));

  // Transient graph structures live in d_out (51.2 MB); all are dead (fully read)
  // before the final gemm overwrites d_out (stream-ordered). Placement verified in r12.
  uint* dout_u   = (uint*)d_out;
  uint* ebuf     = dout_u;                   // [0, 1.64M)   6.55 MB
  uint* ebuf2    = dout_u + 1700000;         // [1.7M, 3.3M) 6.4 MB
  uint* csr      = dout_u + 3400000;         // [3.4M, 5.0M) 6.4 MB
  int*  rowstart = (int*)(dout_u + 5100000); // [5.1M, 5.2M) 400 KB

  const int* src_idx = eidx;
  const int* dst_idx = eidx + NE;

  hipMemsetAsync(cnt8, 0, NBKT * sizeof(uint), stream);
  hipMemsetAsync(bincnt, 0, NBIN * sizeof(uint), stream);

  cvt2_kernel<<<192, 256, 0, stream>>>(Wl, wlb, Wr, wrb, 3 * HD * HD);

  proj_mfma_kernel<<<(NSRC + 127) / 128, 256, 0, stream>>>(src_x, Wsrc, bsrc, hbuf, NSRC, 0);
  proj_mfma_kernel<<<(NTGT + 127) / 128, 256, 0, stream>>>(tgt_x, Wtgt, btgt, hbuf, NTGT, NSRC);

  part8_kernel<<<PBLKS, 256, 0, stream>>>(src_idx, dst_idx, cnt8, ebuf);
  part2a_kernel<<<NBKT * NCH2, 256, 0, stream>>>(cnt8, ebuf, bincnt);
  scan_kernel<<<1, 256, 0, stream>>>(bincnt, binoff, bincur);
  part2b_kernel<<<NBKT * NCH2, 256, 0, stream>>>(cnt8, ebuf, bincur, ebuf2);
  part3_kernel<<<NBIN, 256, 0, stream>>>(binoff, ebuf2, csr, rowstart);

  const int agrid = NTOT / 16;   // 6250
  const int ggrid = (NTOT + 127) / 128;
  // layer 0: hbuf -> agg(abuf) -> gemm in place over abuf
  agg4_kernel<<<agrid, 256, 0, stream>>>(hbuf, abuf, rowstart, csr);
  mfma_gemm_kernel<<<ggrid, 256, 0, stream>>>(abuf, hbuf, wlb, bl, wrb, abuf, 1, 0);
  // layer 1: abuf -> agg(hbuf) -> gemm in place over hbuf
  agg4_kernel<<<agrid, 256, 0, stream>>>(abuf, hbuf, rowstart, csr);
  mfma_gemm_kernel<<<ggrid, 256, 0, stream>>>(hbuf, abuf, wlb + HD * HD, bl + HD, wrb + HD * HD, hbuf, 1, 0);
  // layer 2: hbuf -> agg(abuf) -> gemm -> d_out (f32, no relu); d_out transients dead here
  agg4_kernel<<<agrid, 256, 0, stream>>>(hbuf, abuf, rowstart, csr);
  mfma_gemm_kernel<<<ggrid, 256, 0, stream>>>(abuf, hbuf, wlb + 2 * HD * HD, bl + 2 * HD, wrb + 2 * HD * HD, out, 0, 1);
}

// Round 14
// 406.411 us; speedup vs baseline: 1.1898x; 1.0130x over previous
//
#include <hip/hip_runtime.h>

#define NSRC 50000
#define NTGT 50000
#define NTOT 100000
#define NE   1600000
#define IND  64
#define HD   128
#define CAP  64        // per-node neighbor capacity in part3 LDS (deg ~ Poisson(16); P(>64) ~ 1e-29)
#define CHUNK2 8192    // edges per part2a/part2b block
#define NCH2 196       // ceil(NE / CHUNK2)
#define SBIN 128       // nodes per level-2 bin
#define NBIN 782       // ceil(NTOT / 128)

typedef short s16x8 __attribute__((ext_vector_type(8)));
typedef float f32x4 __attribute__((ext_vector_type(4)));

__device__ __forceinline__ ushort f2bf(float f) {
  union { float f; uint u; } v; v.f = f;
  const uint r = v.u + 0x7fffu + ((v.u >> 16) & 1u);
  return (ushort)(r >> 16);
}
__device__ __forceinline__ float bfl(uint v) {
  union { uint u; float f; } c; c.u = v << 16; return c.f;
}
__device__ __forceinline__ float bfh(uint v) {
  union { uint u; float f; } c; c.u = v & 0xffff0000u; return c.f;
}

// ---------------- weight conversion f32 -> bf16 (Wl, Wr) ----------------
__global__ __launch_bounds__(256) void cvt2_kernel(const float* __restrict__ a, ushort* __restrict__ oa,
                                                   const float* __restrict__ b, ushort* __restrict__ ob, int n) {
  int i = blockIdx.x * 256 + threadIdx.x;
  const int stride = gridDim.x * 256;
  for (; i < n; i += stride) { oa[i] = f2bf(a[i]); ob[i] = f2bf(b[i]); }
}

// ---------------- MFMA input projection: out[n][f] = bf16(b[f] + x[n][:] @ W[f][:]) ----------------
// W stays f32 (tiny, L2-hot), converted in-register. Block = 128 rows, 4 waves x 32 rows.
__global__ __launch_bounds__(256) void proj_mfma_kernel(
    const float* __restrict__ x, const float* __restrict__ W,
    const float* __restrict__ b, ushort* __restrict__ out,
    const int count, const int out_base) {
  const int lane = threadIdx.x & 63;
  const int wave = threadIdx.x >> 6;
  const int n0 = blockIdx.x * 128 + wave * 32;
  const int lr = lane & 15;
  const int kc = (lane >> 4) * 8;
  const int rowq = (lane >> 4) * 4;

  s16x8 af[2][2];
#pragma unroll
  for (int r = 0; r < 2; ++r) {
    int ar = n0 + 16 * r + lr;
    if (ar >= count) ar = count - 1;
#pragma unroll
    for (int t = 0; t < 2; ++t) {
      const float* xp = x + (size_t)ar * IND + t * 32 + kc;
      const float4 xa = *(const float4*)(xp);
      const float4 xb = *(const float4*)(xp + 4);
      s16x8 a;
      a[0] = (short)f2bf(xa.x); a[1] = (short)f2bf(xa.y);
      a[2] = (short)f2bf(xa.z); a[3] = (short)f2bf(xa.w);
      a[4] = (short)f2bf(xb.x); a[5] = (short)f2bf(xb.y);
      a[6] = (short)f2bf(xb.z); a[7] = (short)f2bf(xb.w);
      af[r][t] = a;
    }
  }
#pragma unroll
  for (int cf = 0; cf < 8; ++cf) {
    const float* wp = W + (size_t)(cf * 16 + lr) * IND + kc;
    s16x8 w0, w1;
    {
      const float4 wa = *(const float4*)(wp);
      const float4 wb = *(const float4*)(wp + 4);
      const float4 wc = *(const float4*)(wp + 32);
      const float4 wd = *(const float4*)(wp + 36);
      w0[0] = (short)f2bf(wa.x); w0[1] = (short)f2bf(wa.y);
      w0[2] = (short)f2bf(wa.z); w0[3] = (short)f2bf(wa.w);
      w0[4] = (short)f2bf(wb.x); w0[5] = (short)f2bf(wb.y);
      w0[6] = (short)f2bf(wb.z); w0[7] = (short)f2bf(wb.w);
      w1[0] = (short)f2bf(wc.x); w1[1] = (short)f2bf(wc.y);
      w1[2] = (short)f2bf(wc.z); w1[3] = (short)f2bf(wc.w);
      w1[4] = (short)f2bf(wd.x); w1[5] = (short)f2bf(wd.y);
      w1[6] = (short)f2bf(wd.z); w1[7] = (short)f2bf(wd.w);
    }
    f32x4 acc0 = {0.f, 0.f, 0.f, 0.f};
    f32x4 acc1 = {0.f, 0.f, 0.f, 0.f};
    acc0 = __builtin_amdgcn_mfma_f32_16x16x32_bf16(af[0][0], w0, acc0, 0, 0, 0);
    acc1 = __builtin_amdgcn_mfma_f32_16x16x32_bf16(af[1][0], w0, acc1, 0, 0, 0);
    acc0 = __builtin_amdgcn_mfma_f32_16x16x32_bf16(af[0][1], w1, acc0, 0, 0, 0);
    acc1 = __builtin_amdgcn_mfma_f32_16x16x32_bf16(af[1][1], w1, acc1, 0, 0, 0);
    const int col = cf * 16 + lr;
    const float bv = b[col];
#pragma unroll
    for (int r = 0; r < 2; ++r) {
      const f32x4 acc = r ? acc1 : acc0;
#pragma unroll
      for (int q = 0; q < 4; ++q) {
        const int row = n0 + 16 * r + rowq + q;
        if (row < count) out[(size_t)(out_base + row) * HD + col] = f2bf(acc[q] + bv);
      }
    }
  }
}

// ---------------- level-2 count per 128-node bin (direct from dst stream) ----------------
__global__ __launch_bounds__(256) void part2a_kernel(const int* __restrict__ dst, uint* __restrict__ bincnt) {
  __shared__ uint hist[NBIN];   // 3.1 KB
  const int tid = threadIdx.x;
  const int i0 = blockIdx.x * CHUNK2;
  const int i1 = (i0 + CHUNK2 < NE) ? i0 + CHUNK2 : NE;
  for (int j = tid; j < NBIN; j += 256) hist[j] = 0;
  __syncthreads();
  for (int i = i0 + tid; i < i1; i += 256)
    atomicAdd(&hist[((uint)dst[i]) >> 7], 1u);
  __syncthreads();
  for (int j = tid; j < NBIN; j += 256)
    if (hist[j]) atomicAdd(&bincnt[j], hist[j]);
}

// ---------------- exclusive scan of bincnt -> binoff (packed, exact); init bincur ----------------
__global__ __launch_bounds__(256) void scan_kernel(const uint* __restrict__ bincnt,
                                                   uint* __restrict__ binoff, uint* __restrict__ bincur) {
  __shared__ uint lds[256];
  const int tid = threadIdx.x;
  uint v[4]; uint s = 0;
#pragma unroll
  for (int j = 0; j < 4; ++j) {
    const int idx = tid * 4 + j;
    v[j] = (idx < NBIN) ? bincnt[idx] : 0;
    s += v[j];
  }
  lds[tid] = s;
  __syncthreads();
  for (int off = 1; off < 256; off <<= 1) {
    const uint t = (tid >= off) ? lds[tid - off] : 0;
    __syncthreads();
    lds[tid] += t;
    __syncthreads();
  }
  uint run = lds[tid] - s;  // exclusive
#pragma unroll
  for (int j = 0; j < 4; ++j) {
    const int idx = tid * 4 + j;
    if (idx < NBIN) { binoff[idx] = run; bincur[idx] = run; }
    else if (idx == NBIN) binoff[idx] = run;
    run += v[j];
  }
}

// ---------------- level-2 scatter (direct): edges -> ebuf2 grouped by bin (ranked) ----------------
// Record = src (17b) | binLocal (7b) << 17, bin = dst>>7. Per-block per-bin runs are
// contiguous (~10 records), so the scatter writes mostly-full lines.
__global__ __launch_bounds__(256) void part2b_kernel(const int* __restrict__ src, const int* __restrict__ dst,
                                                     uint* __restrict__ bincur, uint* __restrict__ ebuf2) {
  __shared__ uint hist[NBIN];   // 3.1 KB
  __shared__ uint base[NBIN];   // 3.1 KB
  const int tid = threadIdx.x;
  const int i0 = blockIdx.x * CHUNK2;
  const int i1 = (i0 + CHUNK2 < NE) ? i0 + CHUNK2 : NE;
  for (int j = tid; j < NBIN; j += 256) hist[j] = 0;
  __syncthreads();
  for (int i = i0 + tid; i < i1; i += 256)
    atomicAdd(&hist[((uint)dst[i]) >> 7], 1u);
  __syncthreads();
  for (int j = tid; j < NBIN; j += 256) {
    if (hist[j]) base[j] = atomicAdd(&bincur[j], hist[j]);
    hist[j] = 0;   // reuse as local cursor
  }
  __syncthreads();
  for (int i = i0 + tid; i < i1; i += 256) {
    const uint d = (uint)dst[i];
    const uint bin = d >> 7;
    const uint pos = base[bin] + atomicAdd(&hist[bin], 1u);
    ebuf2[pos] = (uint)src[i] | ((d & 127u) << 17);
  }
}

// ---------------- part3: node-sort each bin's records -> CSR (csr + rowstart), built ONCE ----------------
__global__ __launch_bounds__(256) void part3_kernel(const uint* __restrict__ binoff, const uint* __restrict__ ebuf2,
                                                    uint* __restrict__ csr, int* __restrict__ rowstart) {
  __shared__ uint slotL[SBIN][CAP];   // 32 KB
  __shared__ uint cntL[SBIN];
  __shared__ uint scanL[SBIN];
  const int tid = threadIdx.x;
  const int b = blockIdx.x;
  const int e0 = (int)binoff[b];
  const int e1 = (int)binoff[b + 1];
  for (int j = tid; j < SBIN; j += 256) cntL[j] = 0;
  __syncthreads();
  for (int i = e0 + tid; i < e1; i += 256) {
    const uint rec = ebuf2[i];
    const uint dl = rec >> 17;
    const uint pos = atomicAdd(&cntL[dl], 1u);
    if (pos < CAP) slotL[dl][pos] = rec & 0x1FFFFu;
  }
  __syncthreads();
  if (tid < SBIN) {
    uint cv = cntL[tid];
    scanL[tid] = cv < CAP ? cv : CAP;
  }
  __syncthreads();
  for (int off = 1; off < SBIN; off <<= 1) {
    uint t = 0;
    if (tid < SBIN && tid >= off) t = scanL[tid - off];
    __syncthreads();
    if (tid < SBIN) scanL[tid] += t;
    __syncthreads();
  }
  if (tid < SBIN) {
    const int node = b * SBIN + tid;
    const uint m = (cntL[tid] < CAP) ? cntL[tid] : CAP;
    const uint myoff = (uint)e0 + scanL[tid] - m;   // exclusive
    if (node < NTOT) {
      rowstart[node] = (int)myoff;
      for (uint j = 0; j < m; ++j) csr[myoff + j] = slotL[tid][j];
    }
  }
  if (b == NBIN - 1 && tid == 0) rowstart[NTOT] = e0 + (int)scanL[SBIN - 1];
}

// ---------------- CSR-direct mean aggregation: 16-lane group per node, zero LDS ----------------
// Grid 6250 x 256 (16 nodes/block). Per group: uniform csr reads (same-address
// broadcast), 4 full 256B rows in flight. At the L3->L2 scattered-line supply floor
// (~178 MB compulsory fetch @ ~3 TB/s) — verified across 3 structural variants.
__global__ __launch_bounds__(256) void agg4_kernel(const ushort* __restrict__ h, ushort* __restrict__ agg,
                                                   const int* __restrict__ rowstart, const uint* __restrict__ csr) {
  const int g = threadIdx.x >> 4;        // 0..15
  const int l16 = threadIdx.x & 15;
  const int n = blockIdx.x * 16 + g;     // 6250*16 = 100000 exact
  const int r0 = rowstart[n];
  const int r1 = rowstart[n + 1];
  const uint4* hp = (const uint4*)h;     // row = 16 uint4 (128 bf16)
  float a0 = 0.f, a1 = 0.f, a2 = 0.f, a3 = 0.f, a4 = 0.f, a5 = 0.f, a6 = 0.f, a7 = 0.f;
#define ACC8(v) { a0 += bfl((v).x); a1 += bfh((v).x); a2 += bfl((v).y); a3 += bfh((v).y); \
                  a4 += bfl((v).z); a5 += bfh((v).z); a6 += bfl((v).w); a7 += bfh((v).w); }
  int i = r0;
  for (; i + 4 <= r1; i += 4) {
    const uint s0 = csr[i], s1 = csr[i + 1], s2 = csr[i + 2], s3 = csr[i + 3];
    const uint4 v0 = hp[(size_t)s0 * 16 + l16];
    const uint4 v1 = hp[(size_t)s1 * 16 + l16];
    const uint4 v2 = hp[(size_t)s2 * 16 + l16];
    const uint4 v3 = hp[(size_t)s3 * 16 + l16];
    ACC8(v0); ACC8(v1); ACC8(v2); ACC8(v3);
  }
  for (; i < r1; ++i) {
    const uint4 v = hp[(size_t)csr[i] * 16 + l16];
    ACC8(v);
  }
#undef ACC8
  const int deg = r1 - r0;
  const float sc = 1.0f / (float)(deg > 1 ? deg : 1);
  uint4 o;
  o.x = (uint)f2bf(a0 * sc) | ((uint)f2bf(a1 * sc) << 16);
  o.y = (uint)f2bf(a2 * sc) | ((uint)f2bf(a3 * sc) << 16);
  o.z = (uint)f2bf(a4 * sc) | ((uint)f2bf(a5 * sc) << 16);
  o.w = (uint)f2bf(a6 * sc) | ((uint)f2bf(a7 * sc) << 16);
  ((uint4*)agg)[(size_t)n * 16 + l16] = o;
}

// ---------------- MFMA dual GEMM: out = A@Wl^T + bl + Hm@Wr^T (opt relu, opt f32 out) ----------------
// Block = 128 rows, 4 waves; each wave owns 32 rows x all 128 cols. No LDS.
// In-place safe (out may alias A): each wave loads its own 32 rows into registers
// before any store; no __restrict__ on aliasing pointers.
__global__ __launch_bounds__(256) void mfma_gemm_kernel(
    const ushort* A, const ushort* Hm,
    const ushort* __restrict__ Wl, const float* __restrict__ bl,
    const ushort* __restrict__ Wr, void* outv,
    const int relu, const int f32out) {
  const int lane = threadIdx.x & 63;
  const int wave = threadIdx.x >> 6;
  const int n0 = blockIdx.x * 128 + wave * 32;
  const int lr = lane & 15;
  const int kc = (lane >> 4) * 8;
  const int rowq = (lane >> 4) * 4;

  s16x8 af[2][4], hf[2][4];
#pragma unroll
  for (int r = 0; r < 2; ++r) {
    int ar = n0 + 16 * r + lr;
    if (ar >= NTOT) ar = NTOT - 1;     // clamped lanes never store
    const ushort* ap = A + (size_t)ar * HD + kc;
    const ushort* hp = Hm + (size_t)ar * HD + kc;
#pragma unroll
    for (int t = 0; t < 4; ++t) {
      af[r][t] = *(const s16x8*)(ap + t * 32);
      hf[r][t] = *(const s16x8*)(hp + t * 32);
    }
  }

#pragma unroll
  for (int cf = 0; cf < 8; ++cf) {
    const ushort* wlp = Wl + (size_t)(cf * 16 + lr) * HD + kc;
    const ushort* wrp = Wr + (size_t)(cf * 16 + lr) * HD + kc;
    s16x8 wl[4], wr[4];
#pragma unroll
    for (int t = 0; t < 4; ++t) {
      wl[t] = *(const s16x8*)(wlp + t * 32);
      wr[t] = *(const s16x8*)(wrp + t * 32);
    }
    f32x4 acc0 = {0.f, 0.f, 0.f, 0.f};
    f32x4 acc1 = {0.f, 0.f, 0.f, 0.f};
#pragma unroll
    for (int t = 0; t < 4; ++t) {
      acc0 = __builtin_amdgcn_mfma_f32_16x16x32_bf16(af[0][t], wl[t], acc0, 0, 0, 0);
      acc1 = __builtin_amdgcn_mfma_f32_16x16x32_bf16(af[1][t], wl[t], acc1, 0, 0, 0);
      acc0 = __builtin_amdgcn_mfma_f32_16x16x32_bf16(hf[0][t], wr[t], acc0, 0, 0, 0);
      acc1 = __builtin_amdgcn_mfma_f32_16x16x32_bf16(hf[1][t], wr[t], acc1, 0, 0, 0);
    }
    const float bv = bl[cf * 16 + lr];
    const int col = cf * 16 + lr;
#pragma unroll
    for (int r = 0; r < 2; ++r) {
      const f32x4 acc = r ? acc1 : acc0;
#pragma unroll
      for (int q = 0; q < 4; ++q) {
        const int row = n0 + 16 * r + rowq + q;
        if (row < NTOT) {
          float v = acc[q] + bv;
          if (relu && v < 0.f) v = 0.f;
          if (f32out) ((float*)outv)[(size_t)row * HD + col] = v;
          else        ((ushort*)outv)[(size_t)row * HD + col] = f2bf(v);
        }
      }
    }
  }
}

extern "C" void kernel_launch(void* const* d_in, const int* in_sizes, int n_in,
                              void* d_out, int out_size, void* d_ws, size_t ws_size,
                              hipStream_t stream) {
  const float* src_x = (const float*)d_in[0];
  const float* tgt_x = (const float*)d_in[1];
  const int*   eidx  = (const int*)d_in[2];
  const float* Wsrc  = (const float*)d_in[3];
  const float* bsrc  = (const float*)d_in[4];
  const float* Wtgt  = (const float*)d_in[5];
  const float* btgt  = (const float*)d_in[6];
  const float* Wl    = (const float*)d_in[7];
  const float* bl    = (const float*)d_in[8];
  const float* Wr    = (const float*)d_in[9];
  float* out = (float*)d_out;
  (void)in_sizes; (void)n_in; (void)out_size; (void)ws_size;

  // ws ~52 MB (under round-2-proven ~59.4 MB)
  char* ws = (char*)d_ws;
  size_t off = 0;
  auto alloc = [&](size_t bytes) -> void* {
    void* p = (void*)(ws + off);
    off = (off + bytes + 511) & ~(size_t)511;
    return p;
  };
  ushort* hbuf   = (ushort*)alloc((size_t)NTOT * HD * sizeof(ushort));  // 25.6 MB (row-major)
  ushort* abuf   = (ushort*)alloc((size_t)NTOT * HD * sizeof(ushort));  // 25.6 MB (row-major)
  ushort* wlb    = (ushort*)alloc((size_t)3 * HD * HD * sizeof(ushort));
  ushort* wrb    = (ushort*)alloc((size_t)3 * HD * HD * sizeof(ushort));
  uint*   bincnt = (uint*)alloc(NBIN * sizeof(uint));
  uint*   binoff = (uint*)alloc((NBIN + 1) * sizeof(uint));
  uint*   bincur = (uint*)alloc(NBIN * sizeof(uint));

  // Transient graph structures live in d_out (51.2 MB); all are dead (fully read)
  // before the final gemm overwrites d_out (stream-ordered). Pattern verified r12/r13.
  uint* dout_u   = (uint*)d_out;
  uint* ebuf2    = dout_u;                   // [0, 1.6M)    6.4 MB
  uint* csr      = dout_u + 1700000;         // [1.7M, 3.3M) 6.4 MB
  int*  rowstart = (int*)(dout_u + 3400000); // [3.4M, 3.5M) 400 KB

  const int* src_idx = eidx;
  const int* dst_idx = eidx + NE;

  hipMemsetAsync(bincnt, 0, NBIN * sizeof(uint), stream);

  cvt2_kernel<<<192, 256, 0, stream>>>(Wl, wlb, Wr, wrb, 3 * HD * HD);

  proj_mfma_kernel<<<(NSRC + 127) / 128, 256, 0, stream>>>(src_x, Wsrc, bsrc, hbuf, NSRC, 0);
  proj_mfma_kernel<<<(NTGT + 127) / 128, 256, 0, stream>>>(tgt_x, Wtgt, btgt, hbuf, NTGT, NSRC);

  part2a_kernel<<<NCH2, 256, 0, stream>>>(dst_idx, bincnt);
  scan_kernel<<<1, 256, 0, stream>>>(bincnt, binoff, bincur);
  part2b_kernel<<<NCH2, 256, 0, stream>>>(src_idx, dst_idx, bincur, ebuf2);
  part3_kernel<<<NBIN, 256, 0, stream>>>(binoff, ebuf2, csr, rowstart);

  const int agrid = NTOT / 16;   // 6250
  const int ggrid = (NTOT + 127) / 128;
  // layer 0: hbuf -> agg(abuf) -> gemm in place over abuf
  agg4_kernel<<<agrid, 256, 0, stream>>>(hbuf, abuf, rowstart, csr);
  mfma_gemm_kernel<<<ggrid, 256, 0, stream>>>(abuf, hbuf, wlb, bl, wrb, abuf, 1, 0);
  // layer 1: abuf -> agg(hbuf) -> gemm in place over hbuf
  agg4_kernel<<<agrid, 256, 0, stream>>>(abuf, hbuf, rowstart, csr);
  mfma_gemm_kernel<<<ggrid, 256, 0, stream>>>(hbuf, abuf, wlb + HD * HD, bl + HD, wrb + HD * HD, hbuf, 1, 0);
  // layer 2: hbuf -> agg(abuf) -> gemm -> d_out (f32, no relu); d_out transients dead here
  agg4_kernel<<<agrid, 256, 0, stream>>>(hbuf, abuf, rowstart, csr);
  mfma_gemm_kernel<<<ggrid, 256, 0, stream>>>(abuf, hbuf, wlb + 2 * HD * HD, bl + 2 * HD, wrb + 2 * HD * HD, out, 0, 1);
}